// Round 1
// baseline (2088.364 us; speedup 1.0000x reference)
//
#include <hip/hip_runtime.h>
#include <cmath>

// Problem constants
#define NN 512   // nodes
#define BB 32    // batch
#define HH 64    // hidden
#define TT 12    // timesteps
#define KS 3     // graph supports
#define PP 66    // C + H

// Workspace layout (floats):
//  Xt : [t][j][b*2+c]            12*512*64   = 393216
//  Sx : [t][k][i][b*2+c]         12*3*512*64 = 1179648
//  Hc : [i][b*64+p]              512*2048    = 1048576   (in-place recurrent state)
//  S  : [k][i][b*64+p]           3*512*2048  = 3145728   (reused: Sg then Su)
//  Z  : [i][b*64+p]              512*2048    = 1048576
//  RH : [i][b*64+p]              512*2048    = 1048576
#define OFF_XT  0
#define OFF_SX  393216
#define OFF_HC  1572864
#define OFF_S   2621440
#define OFF_Z   5767168
#define OFF_RH  6815744

__global__ __launch_bounds__(256) void prep_xt(const float* __restrict__ x_seq,
                                               float* __restrict__ Xt) {
  int idx = blockIdx.x * 256 + threadIdx.x;  // t*32768 + j*64 + b*2 + c
  if (idx >= TT * NN * BB * 2) return;
  int c = idx & 1;
  int b = (idx >> 1) & 31;
  int j = (idx >> 6) & 511;
  int t = idx >> 15;
  Xt[idx] = x_seq[(((size_t)b * TT + t) * NN + j) * 2 + c];
}

__global__ __launch_bounds__(256) void prep_h(const float* __restrict__ init_h,
                                              float* __restrict__ Hc) {
  int idx = blockIdx.x * 256 + threadIdx.x;  // i*2048 + b*64 + p
  if (idx >= NN * BB * HH) return;
  int p = idx & 63;
  int b = (idx >> 6) & 31;
  int i = idx >> 11;
  Hc[idx] = init_h[((size_t)b * NN + i) * HH + p];
}

// C = G[k] @ B  with A = G[k] (512x512 row-major), B (512 x NB), C (512 x NB).
// grid: (NB tiles of BN, 8 i-tiles of 64, z batches)
// zmode==0: k = z, B fixed.  zmode==1: k = z%3, B offset (z/3)*bStride.
template <int BN>
__global__ __launch_bounds__(256) void gemm_g(const float* __restrict__ Gm,
                                              const float* __restrict__ Bsrc,
                                              float* __restrict__ Cdst, int NB,
                                              int zmode, int bStride, int cStride) {
  constexpr int TN = BN / 16;
  __shared__ float Ast[32][68];       // A chunk, transposed: Ast[j][i]
  __shared__ float Bs[32][BN + 4];    // B chunk
  int z = blockIdx.z;
  int k, bOff;
  if (zmode == 0) { k = z; bOff = 0; }
  else { k = z % 3; bOff = (z / 3) * bStride; }
  const float* A = Gm + (size_t)k * NN * NN;
  const float* Bm = Bsrc + bOff;
  float* Cm = Cdst + (size_t)z * cStride;
  int i0 = blockIdx.y * 64;
  int c0 = blockIdx.x * BN;
  int tid = threadIdx.x;
  int tx = tid & 15, ty = tid >> 4;
  float acc[4][TN];
#pragma unroll
  for (int r = 0; r < 4; ++r)
#pragma unroll
    for (int c = 0; c < TN; ++c) acc[r][c] = 0.f;

  for (int j0 = 0; j0 < NN; j0 += 32) {
    // stage A 64x32, transposed into LDS
#pragma unroll
    for (int u = 0; u < 2; ++u) {
      int e = tid + u * 256;              // 0..511
      int ai = e >> 3;                    // 0..63
      int aj = (e & 7) * 4;               // 0..28
      float4 v = *(const float4*)(A + (size_t)(i0 + ai) * NN + j0 + aj);
      Ast[aj + 0][ai] = v.x;
      Ast[aj + 1][ai] = v.y;
      Ast[aj + 2][ai] = v.z;
      Ast[aj + 3][ai] = v.w;
    }
    // stage B 32xBN
#pragma unroll
    for (int u = 0; u < (32 * BN / 4) / 256; ++u) {
      int e = tid + u * 256;
      int bj = e / (BN / 4);
      int bc = (e % (BN / 4)) * 4;
      *(float4*)(&Bs[bj][bc]) = *(const float4*)(Bm + (size_t)(j0 + bj) * NB + c0 + bc);
    }
    __syncthreads();
#pragma unroll 4
    for (int kk2 = 0; kk2 < 32; ++kk2) {
      float a[4];
      *(float4*)a = *(const float4*)(&Ast[kk2][ty * 4]);
      float bb[TN];
#pragma unroll
      for (int c = 0; c < TN / 4; ++c)
        *(float4*)(&bb[c * 4]) = *(const float4*)(&Bs[kk2][tx * TN + c * 4]);
#pragma unroll
      for (int r = 0; r < 4; ++r)
#pragma unroll
        for (int c = 0; c < TN; ++c) acc[r][c] = fmaf(a[r], bb[c], acc[r][c]);
    }
    __syncthreads();
  }
#pragma unroll
  for (int r = 0; r < 4; ++r) {
    int i = i0 + ty * 4 + r;
#pragma unroll
    for (int c = 0; c < TN / 4; ++c)
      *(float4*)(Cm + (size_t)i * NB + c0 + tx * TN + c * 4) = *(const float4*)(&acc[r][c * 4]);
  }
}

// Gate epilogue: zr = sigmoid([Sx|Sg] @ Wg + bg); write Z and RH = r*h.
// grid: (8 i-tiles, 32 b). out tile 64 x 128 per block.
__global__ __launch_bounds__(256) void gate_epi(const float* __restrict__ S,
                                                const float* __restrict__ Sx,
                                                const float* __restrict__ Wg,
                                                const float* __restrict__ bg,
                                                const float* __restrict__ Hc,
                                                float* __restrict__ Z,
                                                float* __restrict__ RH, int t) {
  __shared__ float Ast[66][68];   // Ast[kp][i]
  __shared__ float Ws[66][132];
  int b = blockIdx.y;
  int i0 = blockIdx.x * 64;
  int tid = threadIdx.x;
  int tx = tid & 15, ty = tid >> 4;
  float acc[4][8];
#pragma unroll
  for (int r = 0; r < 4; ++r)
#pragma unroll
    for (int c = 0; c < 8; ++c) acc[r][c] = 0.f;

  for (int k = 0; k < KS; ++k) {
    // x-part rows 0..1
    if (tid < 128) {
      int i = tid >> 1, c = tid & 1;
      Ast[c][i] = Sx[(((size_t)t * KS + k) * NN + i0 + i) * 64 + b * 2 + c];
    }
    // h-part rows 2..65 from S (64x64 sub-block)
#pragma unroll
    for (int u = 0; u < 4; ++u) {
      int e = tid + u * 256;             // 0..1023
      int i = e >> 4;                    // 0..63
      int p4 = (e & 15) * 4;             // 0..60
      float4 v = *(const float4*)(S + ((size_t)k * NN + i0 + i) * 2048 + b * 64 + p4);
      Ast[2 + p4 + 0][i] = v.x;
      Ast[2 + p4 + 1][i] = v.y;
      Ast[2 + p4 + 2][i] = v.z;
      Ast[2 + p4 + 3][i] = v.w;
    }
    // W chunk 66x128
    for (int e = tid; e < 66 * 32; e += 256) {
      int row = e >> 5, c4 = (e & 31) * 4;
      *(float4*)(&Ws[row][c4]) = *(const float4*)(Wg + ((size_t)k * PP + row) * 128 + c4);
    }
    __syncthreads();
    for (int kp = 0; kp < 66; ++kp) {
      float a[4];
      *(float4*)a = *(const float4*)(&Ast[kp][ty * 4]);
      float bb[8];
      *(float4*)(&bb[0]) = *(const float4*)(&Ws[kp][tx * 8]);
      *(float4*)(&bb[4]) = *(const float4*)(&Ws[kp][tx * 8 + 4]);
#pragma unroll
      for (int r = 0; r < 4; ++r)
#pragma unroll
        for (int c = 0; c < 8; ++c) acc[r][c] = fmaf(a[r], bb[c], acc[r][c]);
    }
    __syncthreads();
  }
#pragma unroll
  for (int r = 0; r < 4; ++r) {
    int i = i0 + ty * 4 + r;
    size_t base = (size_t)i * 2048 + b * 64;
#pragma unroll
    for (int c = 0; c < 8; ++c) {
      int o = tx * 8 + c;
      float v = acc[r][c] + bg[o];
      v = 1.f / (1.f + __expf(-v));
      if (o < 64) {
        Z[base + o] = v;
      } else {
        int p = o - 64;
        RH[base + p] = v * Hc[base + p];
      }
    }
  }
}

// Update epilogue: hc = tanh([Sx|Su] @ Wu + bu); h' = (1-z)h + z*hc (in place).
// grid: (8 i-tiles, 32 b). out tile 64 x 64 per block.
__global__ __launch_bounds__(256) void upd_epi(const float* __restrict__ S,
                                               const float* __restrict__ Sx,
                                               const float* __restrict__ Wu,
                                               const float* __restrict__ bu,
                                               const float* __restrict__ Z,
                                               float* __restrict__ Hc,
                                               float* __restrict__ out, int t) {
  __shared__ float Ast[66][68];
  __shared__ float Ws[66][68];
  int b = blockIdx.y;
  int i0 = blockIdx.x * 64;
  int tid = threadIdx.x;
  int tx = tid & 15, ty = tid >> 4;
  float acc[4][4];
#pragma unroll
  for (int r = 0; r < 4; ++r)
#pragma unroll
    for (int c = 0; c < 4; ++c) acc[r][c] = 0.f;

  for (int k = 0; k < KS; ++k) {
    if (tid < 128) {
      int i = tid >> 1, c = tid & 1;
      Ast[c][i] = Sx[(((size_t)t * KS + k) * NN + i0 + i) * 64 + b * 2 + c];
    }
#pragma unroll
    for (int u = 0; u < 4; ++u) {
      int e = tid + u * 256;
      int i = e >> 4;
      int p4 = (e & 15) * 4;
      float4 v = *(const float4*)(S + ((size_t)k * NN + i0 + i) * 2048 + b * 64 + p4);
      Ast[2 + p4 + 0][i] = v.x;
      Ast[2 + p4 + 1][i] = v.y;
      Ast[2 + p4 + 2][i] = v.z;
      Ast[2 + p4 + 3][i] = v.w;
    }
    for (int e = tid; e < 66 * 16; e += 256) {
      int row = e >> 4, c4 = (e & 15) * 4;
      *(float4*)(&Ws[row][c4]) = *(const float4*)(Wu + ((size_t)k * PP + row) * 64 + c4);
    }
    __syncthreads();
    for (int kp = 0; kp < 66; ++kp) {
      float a[4];
      *(float4*)a = *(const float4*)(&Ast[kp][ty * 4]);
      float bb[4];
      *(float4*)(&bb[0]) = *(const float4*)(&Ws[kp][tx * 4]);
#pragma unroll
      for (int r = 0; r < 4; ++r)
#pragma unroll
        for (int c = 0; c < 4; ++c) acc[r][c] = fmaf(a[r], bb[c], acc[r][c]);
    }
    __syncthreads();
  }
#pragma unroll
  for (int r = 0; r < 4; ++r) {
    int i = i0 + ty * 4 + r;
    size_t base = (size_t)i * 2048 + b * 64;
#pragma unroll
    for (int c = 0; c < 4; ++c) {
      int o = tx * 4 + c;
      float hc = tanhf(acc[r][c] + bu[o]);
      float z = Z[base + o];
      float h = Hc[base + o];
      float hn = (1.f - z) * h + z * hc;
      Hc[base + o] = hn;
      if (t == TT - 1) out[((size_t)b * NN + i) * HH + o] = hn;
    }
  }
}

extern "C" void kernel_launch(void* const* d_in, const int* in_sizes, int n_in,
                              void* d_out, int out_size, void* d_ws, size_t ws_size,
                              hipStream_t stream) {
  const float* G      = (const float*)d_in[0];
  const float* x_seq  = (const float*)d_in[1];
  const float* init_h = (const float*)d_in[2];
  const float* Wg     = (const float*)d_in[3];
  const float* bg     = (const float*)d_in[4];
  const float* Wu     = (const float*)d_in[5];
  const float* bu     = (const float*)d_in[6];
  float* out = (float*)d_out;
  float* ws = (float*)d_ws;

  float* Xt = ws + OFF_XT;
  float* Sx = ws + OFF_SX;
  float* Hc = ws + OFF_HC;
  float* S  = ws + OFF_S;
  float* Z  = ws + OFF_Z;
  float* RH = ws + OFF_RH;

  // Prologue: layout transforms + x-part precompute (state-independent).
  prep_xt<<<(TT * NN * BB * 2 + 255) / 256, 256, 0, stream>>>(x_seq, Xt);
  prep_h<<<(NN * BB * HH + 255) / 256, 256, 0, stream>>>(init_h, Hc);
  // Sx[t][k] = G[k] @ Xt[t]  (36 GEMMs of 512x512x64)
  gemm_g<64><<<dim3(1, 8, TT * KS), 256, 0, stream>>>(G, Xt, Sx, 64, 1, NN * 64, NN * 64);

  for (int t = 0; t < TT; ++t) {
    // Sg[k] = G[k] @ H   (3 GEMMs of 512x512x2048)
    gemm_g<128><<<dim3(16, 8, KS), 256, 0, stream>>>(G, Hc, S, 2048, 0, 0, NN * 2048);
    gate_epi<<<dim3(8, BB), 256, 0, stream>>>(S, Sx, Wg, bg, Hc, Z, RH, t);
    // Su[k] = G[k] @ RH
    gemm_g<128><<<dim3(16, 8, KS), 256, 0, stream>>>(G, RH, S, 2048, 0, 0, NN * 2048);
    upd_epi<<<dim3(8, BB), 256, 0, stream>>>(S, Sx, Wu, bu, Z, Hc, out, t);
  }
}

// Round 2
// 1331.035 us; speedup vs baseline: 1.5690x; 1.5690x over previous
//
#include <hip/hip_runtime.h>
#include <hip/hip_bf16.h>
#include <cmath>

// Problem constants
#define NN 512   // nodes
#define BB 32    // batch
#define HH 64    // hidden
#define TT 12    // timesteps
#define KS 3     // graph supports
#define PP 66    // C + H
#define GK 1536  // split-GEMM K: [Ghi | Glo | Ghi] x [Bhi ; Bhi ; Blo]

// Workspace layout (float units):
//  RHhi/RHlo : bf16 [2048][512] each (Xt aliases the RHhi region during prologue)
//  Xt  : [t][j][b*2+c]            12*512*64   = 393216   (aliases RHhi)
//  Sx  : [t][k][i][b*2+c]         12*3*512*64 = 1179648
//  S   : [k][i][b*64+p] fp32      3*512*2048  = 3145728
//  Z   : [i][b*64+p]    fp32      512*2048    = 1048576
//  Gp  : bf16 [3][512][1536]                  = 1179648 float-equiv
//  Hhi/Hlo : bf16 [2048][512] each            = 524288 float-equiv each
#define OFF_RHHI 0
#define OFF_XT   0
#define OFF_RHLO 524288
#define OFF_SX   1048576
#define OFF_S    2228224
#define OFF_Z    5373952
#define OFF_GP   6422528
#define OFF_HHI  7602176
#define OFF_HLO  8126464
// total 8650752 floats = 34.6 MB

typedef __attribute__((ext_vector_type(8))) short v8s;     // 8 bf16 (4 VGPRs)
typedef __attribute__((ext_vector_type(4))) float f32x4;   // MFMA C/D
typedef __attribute__((ext_vector_type(4))) unsigned short u16x4;

__device__ inline unsigned short f2bf(float f) {
  union { __hip_bfloat16 h; unsigned short u; } x;
  x.h = __float2bfloat16(f);
  return x.u;
}
__device__ inline float bf2f(unsigned short u) {
  union { unsigned short u; __hip_bfloat16 h; } x;
  x.u = u;
  return __bfloat162float(x.h);
}

// ---------------- prologue kernels ----------------

__global__ __launch_bounds__(256) void pack_g(const float* __restrict__ G,
                                              unsigned short* __restrict__ Gp) {
  int idx = blockIdx.x * 256 + threadIdx.x;  // k*262144 + i*512 + j
  if (idx >= KS * NN * NN) return;
  int j = idx & 511;
  int i = (idx >> 9) & 511;
  int k = idx >> 18;
  float g = G[idx];
  unsigned short hi = f2bf(g);
  unsigned short lo = f2bf(g - bf2f(hi));
  size_t base = ((size_t)k * NN + i) * GK;
  Gp[base + j] = hi;
  Gp[base + 512 + j] = lo;
  Gp[base + 1024 + j] = hi;
}

__global__ __launch_bounds__(256) void prep_xt(const float* __restrict__ x_seq,
                                               float* __restrict__ Xt) {
  int idx = blockIdx.x * 256 + threadIdx.x;  // t*32768 + j*64 + b*2 + c
  if (idx >= TT * NN * BB * 2) return;
  int c = idx & 1;
  int b = (idx >> 1) & 31;
  int j = (idx >> 6) & 511;
  int t = idx >> 15;
  Xt[idx] = x_seq[(((size_t)b * TT + t) * NN + j) * 2 + c];
}

__global__ __launch_bounds__(256) void prep_h2(const float* __restrict__ init_h,
                                               unsigned short* __restrict__ Hhi,
                                               unsigned short* __restrict__ Hlo) {
  int idx = blockIdx.x * 256 + threadIdx.x;  // col*512 + i, col = b*64+p
  if (idx >= 2048 * NN) return;
  int i = idx & 511;
  int col = idx >> 9;
  int b = col >> 6;
  int p = col & 63;
  float h = init_h[((size_t)b * NN + i) * HH + p];
  unsigned short hi = f2bf(h);
  Hhi[idx] = hi;
  Hlo[idx] = f2bf(h - bf2f(hi));
}

// ---------------- fp32 GEMM for the Sx precompute (small, one-time) ----------------
// C = G[k] @ B ; zmode==1: k = z%3, B offset (z/3)*bStride.
template <int BN>
__global__ __launch_bounds__(256) void gemm_g(const float* __restrict__ Gm,
                                              const float* __restrict__ Bsrc,
                                              float* __restrict__ Cdst, int NB,
                                              int zmode, int bStride, int cStride) {
  constexpr int TN = BN / 16;
  __shared__ float Ast[32][68];
  __shared__ float Bs[32][BN + 4];
  int z = blockIdx.z;
  int k, bOff;
  if (zmode == 0) { k = z; bOff = 0; }
  else { k = z % 3; bOff = (z / 3) * bStride; }
  const float* A = Gm + (size_t)k * NN * NN;
  const float* Bm = Bsrc + bOff;
  float* Cm = Cdst + (size_t)z * cStride;
  int i0 = blockIdx.y * 64;
  int c0 = blockIdx.x * BN;
  int tid = threadIdx.x;
  int tx = tid & 15, ty = tid >> 4;
  float acc[4][TN];
#pragma unroll
  for (int r = 0; r < 4; ++r)
#pragma unroll
    for (int c = 0; c < TN; ++c) acc[r][c] = 0.f;

  for (int j0 = 0; j0 < NN; j0 += 32) {
#pragma unroll
    for (int u = 0; u < 2; ++u) {
      int e = tid + u * 256;
      int ai = e >> 3;
      int aj = (e & 7) * 4;
      float4 v = *(const float4*)(A + (size_t)(i0 + ai) * NN + j0 + aj);
      Ast[aj + 0][ai] = v.x;
      Ast[aj + 1][ai] = v.y;
      Ast[aj + 2][ai] = v.z;
      Ast[aj + 3][ai] = v.w;
    }
#pragma unroll
    for (int u = 0; u < (32 * BN / 4) / 256; ++u) {
      int e = tid + u * 256;
      int bj = e / (BN / 4);
      int bc = (e % (BN / 4)) * 4;
      *(float4*)(&Bs[bj][bc]) = *(const float4*)(Bm + (size_t)(j0 + bj) * NB + c0 + bc);
    }
    __syncthreads();
#pragma unroll 4
    for (int kk2 = 0; kk2 < 32; ++kk2) {
      float a[4];
      *(float4*)a = *(const float4*)(&Ast[kk2][ty * 4]);
      float bb[TN];
#pragma unroll
      for (int c = 0; c < TN / 4; ++c)
        *(float4*)(&bb[c * 4]) = *(const float4*)(&Bs[kk2][tx * TN + c * 4]);
#pragma unroll
      for (int r = 0; r < 4; ++r)
#pragma unroll
        for (int c = 0; c < TN; ++c) acc[r][c] = fmaf(a[r], bb[c], acc[r][c]);
    }
    __syncthreads();
  }
#pragma unroll
  for (int r = 0; r < 4; ++r) {
    int i = i0 + ty * 4 + r;
#pragma unroll
    for (int c = 0; c < TN / 4; ++c)
      *(float4*)(Cm + (size_t)i * NB + c0 + tx * TN + c * 4) = *(const float4*)(&acc[r][c * 4]);
  }
}

// ---------------- split-bf16 MFMA GEMM ----------------
// S[k][i][col] = sum_j G[k][i][j] * B[col][j]   (B stored transposed bf16 hi/lo)
// A'' = Gp[k] (512 x 1536), B'' rows: [Bhi ; Bhi ; Blo] (col-major source).
// grid: (16 n-tiles of 128, 4 m-tiles of 128, 3 k)
__global__ __launch_bounds__(256) void gemm_mfma(const unsigned short* __restrict__ Gp,
                                                 const unsigned short* __restrict__ Bhi,
                                                 const unsigned short* __restrict__ Blo,
                                                 float* __restrict__ Sout) {
  __shared__ __align__(16) short sA[128 * 64];  // [row][k] swizzled
  __shared__ __align__(16) short sB[128 * 64];  // [col][k] swizzled
  int k = blockIdx.z;
  int i0 = blockIdx.y * 128;
  int c0 = blockIdx.x * 128;
  int tid = threadIdx.x;
  int lane = tid & 63;
  int w = tid >> 6;
  int wm = (w >> 1) * 64, wn = (w & 1) * 64;
  const unsigned short* Ag = Gp + (size_t)k * NN * GK;

  f32x4 acc[4][4];
#pragma unroll
  for (int m = 0; m < 4; ++m)
#pragma unroll
    for (int n = 0; n < 4; ++n) acc[m][n] = (f32x4)(0.f);

  for (int j0 = 0; j0 < GK; j0 += 64) {
    const unsigned short* Bsel = (j0 < 1024) ? Bhi : Blo;
    int jb = j0 & 511;
    // ---- reg-stage 16KB A + 16KB B (4x 16B chunks per thread each) ----
    v8s ra[4], rb[4];
#pragma unroll
    for (int u = 0; u < 4; ++u) {
      int e = tid + u * 256;
      int row = e >> 3, s8 = e & 7;
      ra[u] = *(const v8s*)(Ag + (size_t)(i0 + row) * GK + j0 + s8 * 8);
      rb[u] = *(const v8s*)(Bsel + (size_t)(c0 + row) * 512 + jb + s8 * 8);
    }
    __syncthreads();  // prior compute done before overwrite
#pragma unroll
    for (int u = 0; u < 4; ++u) {
      int e = tid + u * 256;
      int row = e >> 3, s8 = e & 7;
      int off = row * 64 + ((s8 * 8) ^ ((row & 7) << 3));  // XOR swizzle (shorts)
      *(v8s*)(sA + off) = ra[u];
      *(v8s*)(sB + off) = rb[u];
    }
    __syncthreads();
    // ---- compute: 2 k-frags x 4x4 MFMAs ----
#pragma unroll
    for (int kf = 0; kf < 2; ++kf) {
      int koff = kf * 32 + (lane >> 4) * 8;
      v8s af[4], bfr[4];
#pragma unroll
      for (int m = 0; m < 4; ++m) {
        int row = wm + m * 16 + (lane & 15);
        af[m] = *(const v8s*)(sA + row * 64 + (koff ^ ((row & 7) << 3)));
      }
#pragma unroll
      for (int n = 0; n < 4; ++n) {
        int row = wn + n * 16 + (lane & 15);
        bfr[n] = *(const v8s*)(sB + row * 64 + (koff ^ ((row & 7) << 3)));
      }
#pragma unroll
      for (int m = 0; m < 4; ++m)
#pragma unroll
        for (int n = 0; n < 4; ++n)
          acc[m][n] = __builtin_amdgcn_mfma_f32_16x16x32_bf16(af[m], bfr[n], acc[m][n], 0, 0, 0);
    }
  }
  // ---- store C: row = (lane>>4)*4 + reg, col = lane&15 ----
  float* Cm = Sout + (size_t)k * NN * 2048;
#pragma unroll
  for (int m = 0; m < 4; ++m) {
#pragma unroll
    for (int r = 0; r < 4; ++r) {
      int row = i0 + wm + m * 16 + (lane >> 4) * 4 + r;
#pragma unroll
      for (int n = 0; n < 4; ++n)
        Cm[(size_t)row * 2048 + c0 + wn + n * 16 + (lane & 15)] = acc[m][n][r];
    }
  }
}

// ---------------- epilogues ----------------

// zr = sigmoid([Sx|Sg] @ Wg + bg); write Z (fp32) and RH = r*h as transposed bf16 hi/lo.
__global__ __launch_bounds__(256) void gate_epi(const float* __restrict__ S,
                                                const float* __restrict__ Sx,
                                                const float* __restrict__ Wg,
                                                const float* __restrict__ bg,
                                                const unsigned short* __restrict__ Hhi,
                                                const unsigned short* __restrict__ Hlo,
                                                unsigned short* __restrict__ RHhi,
                                                unsigned short* __restrict__ RHlo,
                                                float* __restrict__ Z, int t) {
  __shared__ float Ast[66][68];   // Ast[kp][i]
  __shared__ float Ws[66][132];
  int b = blockIdx.y;
  int i0 = blockIdx.x * 64;
  int tid = threadIdx.x;
  int tx = tid & 15, ty = tid >> 4;
  float acc[4][8];
#pragma unroll
  for (int r = 0; r < 4; ++r)
#pragma unroll
    for (int c = 0; c < 8; ++c) acc[r][c] = 0.f;

  for (int k = 0; k < KS; ++k) {
    if (tid < 128) {
      int i = tid >> 1, c = tid & 1;
      Ast[c][i] = Sx[(((size_t)t * KS + k) * NN + i0 + i) * 64 + b * 2 + c];
    }
#pragma unroll
    for (int u = 0; u < 4; ++u) {
      int e = tid + u * 256;
      int i = e >> 4;
      int p4 = (e & 15) * 4;
      float4 v = *(const float4*)(S + ((size_t)k * NN + i0 + i) * 2048 + b * 64 + p4);
      Ast[2 + p4 + 0][i] = v.x;
      Ast[2 + p4 + 1][i] = v.y;
      Ast[2 + p4 + 2][i] = v.z;
      Ast[2 + p4 + 3][i] = v.w;
    }
    for (int e = tid; e < 66 * 32; e += 256) {
      int row = e >> 5, c4 = (e & 31) * 4;
      *(float4*)(&Ws[row][c4]) = *(const float4*)(Wg + ((size_t)k * PP + row) * 128 + c4);
    }
    __syncthreads();
    for (int kp = 0; kp < 66; ++kp) {
      float a[4];
      *(float4*)a = *(const float4*)(&Ast[kp][ty * 4]);
      float bb[8];
      *(float4*)(&bb[0]) = *(const float4*)(&Ws[kp][tx * 8]);
      *(float4*)(&bb[4]) = *(const float4*)(&Ws[kp][tx * 8 + 4]);
#pragma unroll
      for (int r = 0; r < 4; ++r)
#pragma unroll
        for (int c = 0; c < 8; ++c) acc[r][c] = fmaf(a[r], bb[c], acc[r][c]);
    }
    __syncthreads();
  }
  float vv[4][8];
#pragma unroll
  for (int r = 0; r < 4; ++r) {
    int i = i0 + ty * 4 + r;
    size_t base = (size_t)i * 2048 + b * 64;
#pragma unroll
    for (int c = 0; c < 8; ++c) {
      int o = tx * 8 + c;
      float v = 1.f / (1.f + __expf(-(acc[r][c] + bg[o])));
      vv[r][c] = v;
      if (o < 64) Z[base + o] = v;
    }
  }
  if (tx >= 8) {  // r-half: produce RH split (transposed)
#pragma unroll
    for (int c = 0; c < 8; ++c) {
      int p = tx * 8 + c - 64;
      size_t cb = ((size_t)b * 64 + p) * 512 + i0 + ty * 4;
      u16x4 h4 = *(const u16x4*)(&Hhi[cb]);
      u16x4 l4 = *(const u16x4*)(&Hlo[cb]);
      u16x4 oh, ol;
#pragma unroll
      for (int r = 0; r < 4; ++r) {
        float h = bf2f(h4[r]) + bf2f(l4[r]);
        float rh = vv[r][c] * h;
        unsigned short hi = f2bf(rh);
        oh[r] = hi;
        ol[r] = f2bf(rh - bf2f(hi));
      }
      *(u16x4*)(&RHhi[cb]) = oh;
      *(u16x4*)(&RHlo[cb]) = ol;
    }
  }
}

// hc = tanh([Sx|Su] @ Wu + bu); h' = (1-z)h + z*hc, stored as transposed bf16 hi/lo.
__global__ __launch_bounds__(256) void upd_epi(const float* __restrict__ S,
                                               const float* __restrict__ Sx,
                                               const float* __restrict__ Wu,
                                               const float* __restrict__ bu,
                                               const float* __restrict__ Z,
                                               unsigned short* __restrict__ Hhi,
                                               unsigned short* __restrict__ Hlo,
                                               float* __restrict__ out, int t) {
  __shared__ float Ast[66][68];
  __shared__ float Ws[66][68];
  int b = blockIdx.y;
  int i0 = blockIdx.x * 64;
  int tid = threadIdx.x;
  int tx = tid & 15, ty = tid >> 4;
  float acc[4][4];
#pragma unroll
  for (int r = 0; r < 4; ++r)
#pragma unroll
    for (int c = 0; c < 4; ++c) acc[r][c] = 0.f;

  for (int k = 0; k < KS; ++k) {
    if (tid < 128) {
      int i = tid >> 1, c = tid & 1;
      Ast[c][i] = Sx[(((size_t)t * KS + k) * NN + i0 + i) * 64 + b * 2 + c];
    }
#pragma unroll
    for (int u = 0; u < 4; ++u) {
      int e = tid + u * 256;
      int i = e >> 4;
      int p4 = (e & 15) * 4;
      float4 v = *(const float4*)(S + ((size_t)k * NN + i0 + i) * 2048 + b * 64 + p4);
      Ast[2 + p4 + 0][i] = v.x;
      Ast[2 + p4 + 1][i] = v.y;
      Ast[2 + p4 + 2][i] = v.z;
      Ast[2 + p4 + 3][i] = v.w;
    }
    for (int e = tid; e < 66 * 16; e += 256) {
      int row = e >> 4, c4 = (e & 15) * 4;
      *(float4*)(&Ws[row][c4]) = *(const float4*)(Wu + ((size_t)k * PP + row) * 64 + c4);
    }
    __syncthreads();
    for (int kp = 0; kp < 66; ++kp) {
      float a[4];
      *(float4*)a = *(const float4*)(&Ast[kp][ty * 4]);
      float bb[4];
      *(float4*)(&bb[0]) = *(const float4*)(&Ws[kp][tx * 4]);
#pragma unroll
      for (int r = 0; r < 4; ++r)
#pragma unroll
        for (int c = 0; c < 4; ++c) acc[r][c] = fmaf(a[r], bb[c], acc[r][c]);
    }
    __syncthreads();
  }
#pragma unroll
  for (int c = 0; c < 4; ++c) {
    int o = tx * 4 + c;
    size_t cb = ((size_t)b * 64 + o) * 512 + i0 + ty * 4;
    u16x4 h4 = *(const u16x4*)(&Hhi[cb]);
    u16x4 l4 = *(const u16x4*)(&Hlo[cb]);
    u16x4 oh, ol;
#pragma unroll
    for (int r = 0; r < 4; ++r) {
      int i = i0 + ty * 4 + r;
      float hc = tanhf(acc[r][c] + bu[o]);
      float z = Z[(size_t)i * 2048 + b * 64 + o];
      float h = bf2f(h4[r]) + bf2f(l4[r]);
      float hn = (1.f - z) * h + z * hc;
      unsigned short hi = f2bf(hn);
      oh[r] = hi;
      ol[r] = f2bf(hn - bf2f(hi));
      if (t == TT - 1) out[((size_t)b * NN + i) * HH + o] = hn;
    }
    *(u16x4*)(&Hhi[cb]) = oh;
    *(u16x4*)(&Hlo[cb]) = ol;
  }
}

extern "C" void kernel_launch(void* const* d_in, const int* in_sizes, int n_in,
                              void* d_out, int out_size, void* d_ws, size_t ws_size,
                              hipStream_t stream) {
  const float* G      = (const float*)d_in[0];
  const float* x_seq  = (const float*)d_in[1];
  const float* init_h = (const float*)d_in[2];
  const float* Wg     = (const float*)d_in[3];
  const float* bg     = (const float*)d_in[4];
  const float* Wu     = (const float*)d_in[5];
  const float* bu     = (const float*)d_in[6];
  float* out = (float*)d_out;
  float* ws = (float*)d_ws;

  float* Xt = ws + OFF_XT;            // aliases RHhi region (prologue-only)
  float* Sx = ws + OFF_SX;
  float* S  = ws + OFF_S;
  float* Z  = ws + OFF_Z;
  unsigned short* Gp   = (unsigned short*)(ws + OFF_GP);
  unsigned short* Hhi  = (unsigned short*)(ws + OFF_HHI);
  unsigned short* Hlo  = (unsigned short*)(ws + OFF_HLO);
  unsigned short* RHhi = (unsigned short*)(ws + OFF_RHHI);
  unsigned short* RHlo = (unsigned short*)(ws + OFF_RHLO);

  // Prologue
  pack_g<<<(KS * NN * NN + 255) / 256, 256, 0, stream>>>(G, Gp);
  prep_xt<<<(TT * NN * BB * 2 + 255) / 256, 256, 0, stream>>>(x_seq, Xt);
  prep_h2<<<(2048 * NN + 255) / 256, 256, 0, stream>>>(init_h, Hhi, Hlo);
  // Sx[t][k] = G[k] @ Xt[t]  (fp32, one-time)
  gemm_g<64><<<dim3(1, 8, TT * KS), 256, 0, stream>>>(G, Xt, Sx, 64, 1, NN * 64, NN * 64);

  for (int t = 0; t < TT; ++t) {
    gemm_mfma<<<dim3(16, 4, KS), 256, 0, stream>>>(Gp, Hhi, Hlo, S);
    gate_epi<<<dim3(8, BB), 256, 0, stream>>>(S, Sx, Wg, bg, Hhi, Hlo, RHhi, RHlo, Z, t);
    gemm_mfma<<<dim3(16, 4, KS), 256, 0, stream>>>(Gp, RHhi, RHlo, S);
    upd_epi<<<dim3(8, BB), 256, 0, stream>>>(S, Sx, Wu, bu, Z, Hhi, Hlo, out, t);
  }
}

// Round 3
// 1030.364 us; speedup vs baseline: 2.0268x; 1.2918x over previous
//
#include <hip/hip_runtime.h>
#include <hip/hip_bf16.h>
#include <cmath>

// Problem constants
#define NN 512   // nodes
#define BB 32    // batch
#define HH 64    // hidden
#define TT 12    // timesteps
#define KS 3     // graph supports
#define GK 1536  // split-GEMM K: [Ghi | Glo | Ghi] x [Bhi ; Bhi ; Blo]

// Workspace layout (float units)
#define OFF_GP    0         // bf16 [1536][1536]  (rows k*512+i)
#define OFF_XTH   1179648   // bf16 [768][512]    Xt hi (col = t*64+b*2+c)
#define OFF_XTL   1376256   // bf16 [768][512]    Xt lo
#define OFF_SX    1572864   // f32  [1536][768]   Sx (row k*512+i, col t*64+b*2+c)
#define OFF_HHI   2752512   // bf16 [2048][512]   h hi (col = b*64+q, row j)
#define OFF_HLO   3276800
#define OFF_RHHI  3801088   // bf16 [2048][512]   r*h hi
#define OFF_RHLO  4325376
#define OFF_Z     4849664   // f32  [32][512][64]
#define OFF_WHGH  5898240   // bf16 [128][200]    W_gate h-rows, o-major, hi
#define OFF_WHGL  5911040
#define OFF_WHUH  5923840   // bf16 [64][200]
#define OFF_WHUL  5930240
#define OFF_WXG   5936640   // f32  [6][128]
#define OFF_WXU   5937408   // f32  [6][64]
// total ~5.94M floats = 23.8 MB

typedef __attribute__((ext_vector_type(8))) short v8s;
typedef __attribute__((ext_vector_type(4))) float f32x4;
typedef __attribute__((ext_vector_type(4))) unsigned short u16x4;

__device__ __forceinline__ unsigned short f2bf(float f) {
  union { __hip_bfloat16 h; unsigned short u; } x;
  x.h = __float2bfloat16(f);
  return x.u;
}
__device__ __forceinline__ float bf2f(unsigned short u) {
  union { unsigned short u; __hip_bfloat16 h; } x;
  x.u = u;
  return __bfloat162float(x.h);
}

// async global->LDS, 16B per lane; LDS dest = wave-uniform base + lane*16
__device__ __forceinline__ void gl_lds16(const unsigned short* g, short* l) {
  __builtin_amdgcn_global_load_lds(
      (const __attribute__((address_space(1))) void*)g,
      (__attribute__((address_space(3))) void*)l, 16, 0, 0);
}

// ---------------- prologue kernels ----------------

__global__ __launch_bounds__(256) void pack_g(const float* __restrict__ G,
                                              unsigned short* __restrict__ Gp) {
  int idx = blockIdx.x * 256 + threadIdx.x;  // k*262144 + i*512 + j
  if (idx >= KS * NN * NN) return;
  int j = idx & 511;
  float g = G[idx];
  unsigned short hi = f2bf(g);
  unsigned short lo = f2bf(g - bf2f(hi));
  size_t base = (size_t)(idx >> 9) * GK;  // row = k*512+i
  Gp[base + j] = hi;
  Gp[base + 512 + j] = lo;
  Gp[base + 1024 + j] = hi;
}

__global__ __launch_bounds__(256) void prep_xt2(const float* __restrict__ x_seq,
                                                unsigned short* __restrict__ Xh,
                                                unsigned short* __restrict__ Xl) {
  int idx = blockIdx.x * 256 + threadIdx.x;  // col*512 + j
  if (idx >= 768 * NN) return;
  int j = idx & 511;
  int col = idx >> 9;          // t*64 + b*2 + c
  int t = col >> 6;
  int b = (col & 63) >> 1;
  int c = col & 1;
  float v = x_seq[((size_t)(b * TT + t) * NN + j) * 2 + c];
  unsigned short hi = f2bf(v);
  Xh[idx] = hi;
  Xl[idx] = f2bf(v - bf2f(hi));
}

__global__ __launch_bounds__(256) void prep_h2(const float* __restrict__ init_h,
                                               unsigned short* __restrict__ Hhi,
                                               unsigned short* __restrict__ Hlo) {
  int idx = blockIdx.x * 256 + threadIdx.x;  // col*512 + i
  if (idx >= 2048 * NN) return;
  int i = idx & 511;
  int col = idx >> 9;
  int b = col >> 6;
  int p = col & 63;
  float h = init_h[((size_t)b * NN + i) * HH + p];
  unsigned short hi = f2bf(h);
  Hhi[idx] = hi;
  Hlo[idx] = f2bf(h - bf2f(hi));
}

__global__ __launch_bounds__(256) void pack_w(const float* __restrict__ Wg,
                                              const float* __restrict__ Wu,
                                              unsigned short* __restrict__ Whgh,
                                              unsigned short* __restrict__ Whgl,
                                              unsigned short* __restrict__ Whuh,
                                              unsigned short* __restrict__ Whul,
                                              float* __restrict__ Wxg,
                                              float* __restrict__ Wxu) {
  int idx = blockIdx.x * 256 + threadIdx.x;
  if (idx < 128 * 192) {
    int o = idx & 127, kq = idx >> 7;
    int k = kq >> 6, q = kq & 63;
    float v = Wg[(size_t)(k * 66 + 2 + q) * 128 + o];
    unsigned short hi = f2bf(v);
    Whgh[o * 200 + kq] = hi;
    Whgl[o * 200 + kq] = f2bf(v - bf2f(hi));
  } else if (idx < 36864) {
    int j = idx - 24576;
    int o = j & 63, kq = j >> 6;
    int k = kq >> 6, q = kq & 63;
    float v = Wu[(size_t)(k * 66 + 2 + q) * 64 + o];
    unsigned short hi = f2bf(v);
    Whuh[o * 200 + kq] = hi;
    Whul[o * 200 + kq] = f2bf(v - bf2f(hi));
  } else if (idx < 37632) {
    int j = idx - 36864;
    int o = j & 127, kc = j >> 7;
    Wxg[kc * 128 + o] = Wg[(size_t)((kc >> 1) * 66 + (kc & 1)) * 128 + o];
  } else if (idx < 38016) {
    int j = idx - 37632;
    int o = j & 63, kc = j >> 6;
    Wxu[kc * 64 + o] = Wu[(size_t)((kc >> 1) * 66 + (kc & 1)) * 64 + o];
  }
}

// ---------------- Sx precompute: Sx = Gp @ [Xhi;Xhi;Xlo], M=1536 N=768 K=1536 ----------------
__global__ __launch_bounds__(256) void gemm_sx(const unsigned short* __restrict__ Gp,
                                               const unsigned short* __restrict__ Xh,
                                               const unsigned short* __restrict__ Xl,
                                               float* __restrict__ Sx2) {
  __shared__ __align__(16) short sA[64 * 64];
  __shared__ __align__(16) short sB[64 * 64];
  int tid = threadIdx.x;
  int L = tid & 63, w = tid >> 6;
  int wm = (w >> 1) * 32, wn = (w & 1) * 32;
  int i0 = blockIdx.y * 64;  // over 1536 rows
  int c0 = blockIdx.x * 64;  // over 768 cols
  f32x4 acc[2][2];
#pragma unroll
  for (int m = 0; m < 2; ++m)
#pragma unroll
    for (int n = 0; n < 2; ++n) acc[m][n] = (f32x4)(0.f);

  for (int j0 = 0; j0 < GK; j0 += 64) {
    const unsigned short* Bsel = (j0 < 1024) ? Xh : Xl;
    int jb = j0 & 511;
    __syncthreads();
#pragma unroll
    for (int u = 0; u < 2; ++u) {
      int r = w * 16 + u * 8;
      gl_lds16(Gp + (size_t)(i0 + r + (L >> 3)) * GK + j0 + (L & 7) * 8, sA + r * 64);
      gl_lds16(Bsel + (size_t)(c0 + r + (L >> 3)) * 512 + jb + (L & 7) * 8, sB + r * 64);
    }
    __syncthreads();
#pragma unroll
    for (int kf = 0; kf < 2; ++kf) {
      int ko = kf * 32 + (L >> 4) * 8;
      v8s af[2], bf[2];
#pragma unroll
      for (int m = 0; m < 2; ++m) af[m] = *(const v8s*)(sA + (wm + m * 16 + (L & 15)) * 64 + ko);
#pragma unroll
      for (int n = 0; n < 2; ++n) bf[n] = *(const v8s*)(sB + (wn + n * 16 + (L & 15)) * 64 + ko);
#pragma unroll
      for (int m = 0; m < 2; ++m)
#pragma unroll
        for (int n = 0; n < 2; ++n)
          acc[m][n] = __builtin_amdgcn_mfma_f32_16x16x32_bf16(af[m], bf[n], acc[m][n], 0, 0, 0);
    }
  }
#pragma unroll
  for (int m = 0; m < 2; ++m)
#pragma unroll
    for (int r = 0; r < 4; ++r)
#pragma unroll
      for (int n = 0; n < 2; ++n)
        Sx2[(size_t)(i0 + wm + m * 16 + (L >> 4) * 4 + r) * 768 + c0 + wn + n * 16 + (L & 15)] =
            acc[m][n][r];
}

// ---------------- fused half-step ----------------
// Block (i-tile 64, b). Main: S[3][64][64] = Gp(rows 3x64) @ Bstate(cols b*64..). K=1536 split.
// Epi: MFMA over K = 3 sections x 192 (S hi/lo x W hi/lo) + fp32 x-part + activation.
template <int GATE>
__global__ __launch_bounds__(256) void fused_step(
    const unsigned short* __restrict__ Gp,
    const unsigned short* __restrict__ Bhi,  // gate: Hhi ; upd: RHhi
    const unsigned short* __restrict__ Blo,
    const float* __restrict__ Sx2,
    const unsigned short* __restrict__ Whi,  // [O][200] o-major
    const unsigned short* __restrict__ Wlo,
    const float* __restrict__ Wx,            // [6][O]
    const float* __restrict__ bias,          // [O]
    const unsigned short* __restrict__ Hr_hi, // h state (read)
    const unsigned short* __restrict__ Hr_lo,
    unsigned short* __restrict__ Ohi,        // gate: RHhi ; upd: Hhi
    unsigned short* __restrict__ Olo,
    float* __restrict__ Z,
    float* __restrict__ out, int t) {
  constexpr int O = GATE ? 128 : 64;
  constexpr int N2 = GATE ? 2 : 1;
  __shared__ __align__(16) char smem[52736];
  short* sA = (short*)smem;                 // [192][64]
  short* sB = (short*)(smem + 24576);       // [64][64]
  short* sS = (short*)smem;                 // overlay: [64][2*200]
  float* sSx = (float*)(smem + 51200);      // [64][6]

  int tid = threadIdx.x;
  int L = tid & 63, w = tid >> 6;
  int i0 = blockIdx.x * 64;
  int b = blockIdx.y;

  // stage Sx slice (region disjoint from sA/sB)
  for (int e = tid; e < 384; e += 256) {
    int il = e / 6, kc = e % 6;
    sSx[e] = Sx2[(size_t)((kc >> 1) * 512 + i0 + il) * 768 + t * 64 + b * 2 + (kc & 1)];
  }

  f32x4 acc[3][4];
#pragma unroll
  for (int m = 0; m < 3; ++m)
#pragma unroll
    for (int n = 0; n < 4; ++n) acc[m][n] = (f32x4)(0.f);

  for (int j0 = 0; j0 < GK; j0 += 64) {
    const unsigned short* Bsel = (j0 < 1024) ? Bhi : Blo;
    int jb = j0 & 511;
    __syncthreads();  // prior compute done before overwrite
    // A: wave w stages rows w*48 .. w*48+47 (3 k-groups x 64 i-rows total)
#pragma unroll
    for (int u = 0; u < 6; ++u) {
      int r = w * 48 + u * 8;
      int gr = r + (L >> 3);
      gl_lds16(Gp + (size_t)((gr >> 6) * 512 + i0 + (gr & 63)) * GK + j0 + (L & 7) * 8,
               sA + r * 64);
    }
    // B: wave w stages cols w*16 .. w*16+15
#pragma unroll
    for (int u = 0; u < 2; ++u) {
      int r = w * 16 + u * 8;
      gl_lds16(Bsel + (size_t)(b * 64 + r + (L >> 3)) * 512 + jb + (L & 7) * 8, sB + r * 64);
    }
    __syncthreads();
#pragma unroll
    for (int kf = 0; kf < 2; ++kf) {
      int ko = kf * 32 + (L >> 4) * 8;
      v8s af[3], bf[4];
#pragma unroll
      for (int m = 0; m < 3; ++m)
        af[m] = *(const v8s*)(sA + (w * 48 + m * 16 + (L & 15)) * 64 + ko);
#pragma unroll
      for (int n = 0; n < 4; ++n) bf[n] = *(const v8s*)(sB + (n * 16 + (L & 15)) * 64 + ko);
#pragma unroll
      for (int m = 0; m < 3; ++m)
#pragma unroll
        for (int n = 0; n < 4; ++n)
          acc[m][n] = __builtin_amdgcn_mfma_f32_16x16x32_bf16(af[m], bf[n], acc[m][n], 0, 0, 0);
    }
  }
  __syncthreads();  // sA/sB dead; write S overlay
#pragma unroll
  for (int m = 0; m < 3; ++m)
#pragma unroll
    for (int n = 0; n < 4; ++n)
#pragma unroll
      for (int r = 0; r < 4; ++r) {
        int R = w * 48 + m * 16 + (L >> 4) * 4 + r;
        int il = R & 63, kk = R >> 6;
        int p = n * 16 + (L & 15);
        float v = acc[m][n][r];
        unsigned short hi = f2bf(v);
        sS[il * 400 + kk * 64 + p] = (short)hi;
        sS[il * 400 + 200 + kk * 64 + p] = (short)f2bf(v - bf2f(hi));
      }
  __syncthreads();

  // ---- epilogue MFMA: zr[64][O] over K = 3 x 192 ----
  int wn = w * (O / 4);
  f32x4 acc2[4][N2];
#pragma unroll
  for (int m = 0; m < 4; ++m)
#pragma unroll
    for (int n = 0; n < N2; ++n) acc2[m][n] = (f32x4)(0.f);

#pragma unroll
  for (int s = 0; s < 3; ++s) {
    const unsigned short* Wsrc = (s < 2) ? Whi : Wlo;
    int abase = (s == 1) ? 200 : 0;
#pragma unroll
    for (int f = 0; f < 6; ++f) {
      int k0 = f * 32 + (L >> 4) * 8;
      v8s af2[4], bf2[N2];
#pragma unroll
      for (int m = 0; m < 4; ++m)
        af2[m] = *(const v8s*)(sS + (m * 16 + (L & 15)) * 400 + abase + k0);
#pragma unroll
      for (int n = 0; n < N2; ++n)
        bf2[n] = *(const v8s*)(Wsrc + (size_t)(wn + n * 16 + (L & 15)) * 200 + k0);
#pragma unroll
      for (int m = 0; m < 4; ++m)
#pragma unroll
        for (int n = 0; n < N2; ++n)
          acc2[m][n] = __builtin_amdgcn_mfma_f32_16x16x32_bf16(af2[m], bf2[n], acc2[m][n], 0, 0, 0);
    }
  }

  // ---- x-part + bias + activation + state update ----
#pragma unroll
  for (int m = 0; m < 4; ++m) {
#pragma unroll
    for (int n = 0; n < N2; ++n) {
      int o = wn + n * 16 + (L & 15);
      float vals[4];
#pragma unroll
      for (int r = 0; r < 4; ++r) {
        int il = m * 16 + (L >> 4) * 4 + r;
        float v = acc2[m][n][r] + bias[o];
#pragma unroll
        for (int kc = 0; kc < 6; ++kc) v += sSx[il * 6 + kc] * Wx[kc * O + o];
        vals[r] = v;
      }
      if (GATE) {
        float sg[4];
#pragma unroll
        for (int r = 0; r < 4; ++r) sg[r] = 1.f / (1.f + __expf(-vals[r]));
        if (o < 64) {
#pragma unroll
          for (int r = 0; r < 4; ++r) {
            int il = m * 16 + (L >> 4) * 4 + r;
            Z[((size_t)b * 512 + i0 + il) * 64 + o] = sg[r];
          }
        } else {
          size_t cb = ((size_t)b * 64 + (o - 64)) * 512 + i0 + m * 16 + (L >> 4) * 4;
          u16x4 h4 = *(const u16x4*)(Hr_hi + cb);
          u16x4 l4 = *(const u16x4*)(Hr_lo + cb);
          u16x4 oh, ol;
#pragma unroll
          for (int r = 0; r < 4; ++r) {
            float h = bf2f(h4[r]) + bf2f(l4[r]);
            float rh = sg[r] * h;
            unsigned short hi = f2bf(rh);
            oh[r] = hi;
            ol[r] = f2bf(rh - bf2f(hi));
          }
          *(u16x4*)(Ohi + cb) = oh;
          *(u16x4*)(Olo + cb) = ol;
        }
      } else {
        size_t cb = ((size_t)b * 64 + o) * 512 + i0 + m * 16 + (L >> 4) * 4;
        u16x4 h4 = *(const u16x4*)(Hr_hi + cb);
        u16x4 l4 = *(const u16x4*)(Hr_lo + cb);
        u16x4 oh, ol;
#pragma unroll
        for (int r = 0; r < 4; ++r) {
          int il = m * 16 + (L >> 4) * 4 + r;
          float hc = tanhf(vals[r]);
          float z = Z[((size_t)b * 512 + i0 + il) * 64 + o];
          float h = bf2f(h4[r]) + bf2f(l4[r]);
          float hn = (1.f - z) * h + z * hc;
          unsigned short hi = f2bf(hn);
          oh[r] = hi;
          ol[r] = f2bf(hn - bf2f(hi));
          if (t == TT - 1) out[((size_t)b * 512 + i0 + il) * 64 + o] = hn;
        }
        *(u16x4*)(Ohi + cb) = oh;
        *(u16x4*)(Olo + cb) = ol;
      }
    }
  }
}

extern "C" void kernel_launch(void* const* d_in, const int* in_sizes, int n_in,
                              void* d_out, int out_size, void* d_ws, size_t ws_size,
                              hipStream_t stream) {
  const float* G      = (const float*)d_in[0];
  const float* x_seq  = (const float*)d_in[1];
  const float* init_h = (const float*)d_in[2];
  const float* Wg     = (const float*)d_in[3];
  const float* bg     = (const float*)d_in[4];
  const float* Wu     = (const float*)d_in[5];
  const float* bu     = (const float*)d_in[6];
  float* out = (float*)d_out;
  float* ws = (float*)d_ws;

  unsigned short* Gp   = (unsigned short*)(ws + OFF_GP);
  unsigned short* Xh   = (unsigned short*)(ws + OFF_XTH);
  unsigned short* Xl   = (unsigned short*)(ws + OFF_XTL);
  float* Sx2           = ws + OFF_SX;
  unsigned short* Hhi  = (unsigned short*)(ws + OFF_HHI);
  unsigned short* Hlo  = (unsigned short*)(ws + OFF_HLO);
  unsigned short* RHhi = (unsigned short*)(ws + OFF_RHHI);
  unsigned short* RHlo = (unsigned short*)(ws + OFF_RHLO);
  float* Z             = ws + OFF_Z;
  unsigned short* Whgh = (unsigned short*)(ws + OFF_WHGH);
  unsigned short* Whgl = (unsigned short*)(ws + OFF_WHGL);
  unsigned short* Whuh = (unsigned short*)(ws + OFF_WHUH);
  unsigned short* Whul = (unsigned short*)(ws + OFF_WHUL);
  float* Wxg           = ws + OFF_WXG;
  float* Wxu           = ws + OFF_WXU;

  // Prologue
  pack_g<<<3072, 256, 0, stream>>>(G, Gp);
  prep_xt2<<<1536, 256, 0, stream>>>(x_seq, Xh, Xl);
  prep_h2<<<4096, 256, 0, stream>>>(init_h, Hhi, Hlo);
  pack_w<<<149, 256, 0, stream>>>(Wg, Wu, Whgh, Whgl, Whuh, Whul, Wxg, Wxu);
  gemm_sx<<<dim3(12, 24), 256, 0, stream>>>(Gp, Xh, Xl, Sx2);

  for (int t = 0; t < TT; ++t) {
    fused_step<1><<<dim3(8, 32), 256, 0, stream>>>(Gp, Hhi, Hlo, Sx2, Whgh, Whgl, Wxg, bg,
                                                   Hhi, Hlo, RHhi, RHlo, Z, out, t);
    fused_step<0><<<dim3(8, 32), 256, 0, stream>>>(Gp, RHhi, RHlo, Sx2, Whuh, Whul, Wxu, bu,
                                                   Hhi, Hlo, Hhi, Hlo, Z, out, t);
  }
}

// Round 4
// 558.171 us; speedup vs baseline: 3.7414x; 1.8460x over previous
//
#include <hip/hip_runtime.h>
#include <hip/hip_bf16.h>
#include <cmath>

// Problem constants
#define NN 512   // nodes
#define BB 32    // batch
#define HH 64    // hidden
#define TT 12    // timesteps
#define KS 3     // graph supports

// Workspace layout (float units)
#define OFF_GHI   0         // bf16 [1536][512]  rows k*512+i, swizzled in j
#define OFF_GLO   393216
#define OFF_XTH   786432    // bf16 [768][512]   col = t*64+b*2+c, swizzled in j
#define OFF_XTL   983040
#define OFF_SX    1179648   // f32  [1536][768]
#define OFF_HHI   2359296   // bf16 [2048][512]  col = b*64+q, swizzled in j(=i)
#define OFF_HLO   2883584
#define OFF_RHHI  3407872
#define OFF_RHLO  3932160
#define OFF_Z     4456448   // f32  [32][512][64]
#define OFF_WHGH  5505024   // bf16 [128][200]
#define OFF_WHGL  5517824
#define OFF_WHUH  5530624   // bf16 [64][200]
#define OFF_WHUL  5537024
#define OFF_WXG   5543424   // f32 [6][128]
#define OFF_WXU   5544192   // f32 [6][64]
// total 5544576 floats = 22.2 MB

typedef __attribute__((ext_vector_type(8))) short v8s;
typedef __attribute__((ext_vector_type(4))) float f32x4;
typedef __attribute__((ext_vector_type(4))) unsigned short u16x4;

__device__ __forceinline__ unsigned short f2bf(float f) {
  union { __hip_bfloat16 h; unsigned short u; } x;
  x.h = __float2bfloat16(f);
  return x.u;
}
__device__ __forceinline__ float bf2f(unsigned short u) {
  union { unsigned short u; __hip_bfloat16 h; } x;
  x.u = u;
  return __bfloat162float(x.h);
}

// XOR-swizzle within each 64-element chunk: group-of-8 g -> g ^ key (key = row&7).
__device__ __forceinline__ int swz64(int j, int key) {
  return (j & ~63) | ((((j >> 3) & 7) ^ key) << 3) | (j & 7);
}

// async global->LDS, 16B/lane; LDS dest = wave-uniform base + lane*16 (linear)
__device__ __forceinline__ void gl_lds16(const unsigned short* g, short* l) {
  __builtin_amdgcn_global_load_lds(
      (const __attribute__((address_space(1))) void*)g,
      (__attribute__((address_space(3))) void*)l, 16, 0, 0);
}

// ---------------- prologue kernels ----------------

__global__ __launch_bounds__(256) void pack_g(const float* __restrict__ G,
                                              unsigned short* __restrict__ Ghi,
                                              unsigned short* __restrict__ Glo) {
  int idx = blockIdx.x * 256 + threadIdx.x;  // k*262144 + i*512 + j
  if (idx >= KS * NN * NN) return;
  int j = idx & 511;
  int i = (idx >> 9) & 511;
  float g = G[idx];
  unsigned short hi = f2bf(g);
  unsigned short lo = f2bf(g - bf2f(hi));
  size_t pos = (size_t)(idx >> 9) * 512 + swz64(j, i & 7);  // row = k*512+i
  Ghi[pos] = hi;
  Glo[pos] = lo;
}

__global__ __launch_bounds__(256) void prep_xt2(const float* __restrict__ x_seq,
                                                unsigned short* __restrict__ Xh,
                                                unsigned short* __restrict__ Xl) {
  int idx = blockIdx.x * 256 + threadIdx.x;  // col*512 + j
  if (idx >= 768 * NN) return;
  int j = idx & 511;
  int col = idx >> 9;          // t*64 + b*2 + c
  int t = col >> 6;
  int b = (col & 63) >> 1;
  int c = col & 1;
  float v = x_seq[((size_t)(b * TT + t) * NN + j) * 2 + c];
  unsigned short hi = f2bf(v);
  size_t pos = (size_t)col * 512 + swz64(j, col & 7);
  Xh[pos] = hi;
  Xl[pos] = f2bf(v - bf2f(hi));
}

__global__ __launch_bounds__(256) void prep_h2(const float* __restrict__ init_h,
                                               unsigned short* __restrict__ Hhi,
                                               unsigned short* __restrict__ Hlo) {
  int idx = blockIdx.x * 256 + threadIdx.x;  // col*512 + i
  if (idx >= 2048 * NN) return;
  int i = idx & 511;
  int col = idx >> 9;
  int b = col >> 6;
  int p = col & 63;
  float h = init_h[((size_t)b * NN + i) * HH + p];
  unsigned short hi = f2bf(h);
  size_t pos = (size_t)col * 512 + swz64(i, col & 7);
  Hhi[pos] = hi;
  Hlo[pos] = f2bf(h - bf2f(hi));
}

__global__ __launch_bounds__(256) void pack_w(const float* __restrict__ Wg,
                                              const float* __restrict__ Wu,
                                              unsigned short* __restrict__ Whgh,
                                              unsigned short* __restrict__ Whgl,
                                              unsigned short* __restrict__ Whuh,
                                              unsigned short* __restrict__ Whul,
                                              float* __restrict__ Wxg,
                                              float* __restrict__ Wxu) {
  int idx = blockIdx.x * 256 + threadIdx.x;
  if (idx < 128 * 192) {
    int o = idx & 127, kq = idx >> 7;
    int k = kq >> 6, q = kq & 63;
    float v = Wg[(size_t)(k * 66 + 2 + q) * 128 + o];
    unsigned short hi = f2bf(v);
    Whgh[o * 200 + kq] = hi;
    Whgl[o * 200 + kq] = f2bf(v - bf2f(hi));
  } else if (idx < 36864) {
    int j = idx - 24576;
    int o = j & 63, kq = j >> 6;
    int k = kq >> 6, q = kq & 63;
    float v = Wu[(size_t)(k * 66 + 2 + q) * 64 + o];
    unsigned short hi = f2bf(v);
    Whuh[o * 200 + kq] = hi;
    Whul[o * 200 + kq] = f2bf(v - bf2f(hi));
  } else if (idx < 37632) {
    int j = idx - 36864;
    int o = j & 127, kc = j >> 7;
    Wxg[kc * 128 + o] = Wg[(size_t)((kc >> 1) * 66 + (kc & 1)) * 128 + o];
  } else if (idx < 38016) {
    int j = idx - 37632;
    int o = j & 63, kc = j >> 6;
    Wxu[kc * 64 + o] = Wu[(size_t)((kc >> 1) * 66 + (kc & 1)) * 64 + o];
  }
}

// ---------------- Sx precompute: M=1536 N=768, 3 combo sections ----------------
__global__ __launch_bounds__(256) void gemm_sx(const unsigned short* __restrict__ Ghi,
                                               const unsigned short* __restrict__ Glo,
                                               const unsigned short* __restrict__ Xh,
                                               const unsigned short* __restrict__ Xl,
                                               float* __restrict__ Sx2) {
  __shared__ __align__(16) short sA[64 * 64];
  __shared__ __align__(16) short sB[64 * 64];
  int tid = threadIdx.x;
  int L = tid & 63, w = tid >> 6;
  int wm = (w >> 1) * 32, wn = (w & 1) * 32;
  int i0 = blockIdx.y * 64;  // over 1536 rows
  int c0 = blockIdx.x * 64;  // over 768 cols
  f32x4 acc[2][2];
#pragma unroll
  for (int m = 0; m < 2; ++m)
#pragma unroll
    for (int n = 0; n < 2; ++n) acc[m][n] = (f32x4)(0.f);

  for (int j0 = 0; j0 < 1536; j0 += 64) {
    const unsigned short* Asel = (j0 < 512 || j0 >= 1024) ? Ghi : Glo;
    const unsigned short* Bsel = (j0 < 1024) ? Xh : Xl;
    int jb = j0 & 511;
    __syncthreads();
#pragma unroll
    for (int u = 0; u < 2; ++u) {
      int r = w * 16 + u * 8;
      gl_lds16(Asel + (size_t)(i0 + r + (L >> 3)) * 512 + jb + (L & 7) * 8, sA + r * 64);
      gl_lds16(Bsel + (size_t)(c0 + r + (L >> 3)) * 512 + jb + (L & 7) * 8, sB + r * 64);
    }
    __syncthreads();
#pragma unroll
    for (int kf = 0; kf < 2; ++kf) {
      int kog = kf * 4 + (L >> 4);
      v8s af[2], bf[2];
#pragma unroll
      for (int m = 0; m < 2; ++m) {
        int row = wm + m * 16 + (L & 15);
        af[m] = *(const v8s*)(sA + row * 64 + ((kog ^ (row & 7)) << 3));
      }
#pragma unroll
      for (int n = 0; n < 2; ++n) {
        int row = wn + n * 16 + (L & 15);
        bf[n] = *(const v8s*)(sB + row * 64 + ((kog ^ (row & 7)) << 3));
      }
#pragma unroll
      for (int m = 0; m < 2; ++m)
#pragma unroll
        for (int n = 0; n < 2; ++n)
          acc[m][n] = __builtin_amdgcn_mfma_f32_16x16x32_bf16(af[m], bf[n], acc[m][n], 0, 0, 0);
    }
  }
#pragma unroll
  for (int m = 0; m < 2; ++m)
#pragma unroll
    for (int r = 0; r < 4; ++r)
#pragma unroll
      for (int n = 0; n < 2; ++n)
        Sx2[(size_t)(i0 + wm + m * 16 + (L >> 4) * 4 + r) * 768 + c0 + wn + n * 16 + (L & 15)] =
            acc[m][n][r];
}

// ---------------- fused half-step ----------------
// LDS shorts layout: AH[2][12288] @0, AL[2][12288] @24576, BH[2][4096] @49152,
// BL[2][4096] @57344 (total 65536 shorts = 128KB). sS overlays @0 ([64][408],
// hi 0..191, lo 200..391). sSx floats @ byte 131072.
__device__ __forceinline__ void stage_tiles(short* sm2, int buf, int j0,
                                            const unsigned short* GH,
                                            const unsigned short* GL,
                                            const unsigned short* BH,
                                            const unsigned short* BL,
                                            int i0, int bcol, int L, int w) {
  short* aH = sm2 + buf * 12288;
  short* aL = sm2 + 24576 + buf * 12288;
  short* bH = sm2 + 49152 + buf * 4096;
  short* bL = sm2 + 57344 + buf * 4096;
#pragma unroll
  for (int u = 0; u < 6; ++u) {
    int r = w * 48 + u * 8;
    int gr = r + (L >> 3);
    size_t gro = (size_t)((gr >> 6) * 512 + i0 + (gr & 63)) * 512 + j0 + (L & 7) * 8;
    gl_lds16(GH + gro, aH + r * 64);
    gl_lds16(GL + gro, aL + r * 64);
  }
#pragma unroll
  for (int u = 0; u < 2; ++u) {
    int r = w * 16 + u * 8;
    size_t gro = (size_t)(bcol + r + (L >> 3)) * 512 + j0 + (L & 7) * 8;
    gl_lds16(BH + gro, bH + r * 64);
    gl_lds16(BL + gro, bL + r * 64);
  }
}

__device__ __forceinline__ void mainloop_compute(const short* sm2, int cur, int L, int w,
                                                 f32x4 (&acc)[3][4]) {
  const short* aH = sm2 + cur * 12288;
  const short* aL = sm2 + 24576 + cur * 12288;
  const short* bH = sm2 + 49152 + cur * 4096;
  const short* bL = sm2 + 57344 + cur * 4096;
#pragma unroll
  for (int kf = 0; kf < 2; ++kf) {
    int kog = kf * 4 + (L >> 4);
    v8s ah[3], al[3], bh[4], bl[4];
#pragma unroll
    for (int m = 0; m < 3; ++m) {
      int row = w * 48 + m * 16 + (L & 15);
      int off = row * 64 + ((kog ^ (row & 7)) << 3);
      ah[m] = *(const v8s*)(aH + off);
      al[m] = *(const v8s*)(aL + off);
    }
#pragma unroll
    for (int n = 0; n < 4; ++n) {
      int row = n * 16 + (L & 15);
      int off = row * 64 + ((kog ^ (row & 7)) << 3);
      bh[n] = *(const v8s*)(bH + off);
      bl[n] = *(const v8s*)(bL + off);
    }
#pragma unroll
    for (int m = 0; m < 3; ++m)
#pragma unroll
      for (int n = 0; n < 4; ++n) {
        acc[m][n] = __builtin_amdgcn_mfma_f32_16x16x32_bf16(ah[m], bh[n], acc[m][n], 0, 0, 0);
        acc[m][n] = __builtin_amdgcn_mfma_f32_16x16x32_bf16(al[m], bh[n], acc[m][n], 0, 0, 0);
        acc[m][n] = __builtin_amdgcn_mfma_f32_16x16x32_bf16(ah[m], bl[n], acc[m][n], 0, 0, 0);
      }
  }
}

template <int GATE>
__global__ __launch_bounds__(256, 1) void fused_step(
    const unsigned short* __restrict__ GH,
    const unsigned short* __restrict__ GL,
    const unsigned short* __restrict__ Bhi,  // gate: Hhi ; upd: RHhi
    const unsigned short* __restrict__ Blo,
    const float* __restrict__ Sx2,
    const unsigned short* __restrict__ Whi,  // [O][200]
    const unsigned short* __restrict__ Wlo,
    const float* __restrict__ Wx,            // [6][O]
    const float* __restrict__ bias,          // [O]
    const unsigned short* __restrict__ Hr_hi,
    const unsigned short* __restrict__ Hr_lo,
    unsigned short* __restrict__ Ohi,        // gate: RHhi ; upd: Hhi
    unsigned short* __restrict__ Olo,
    float* __restrict__ Z,
    float* __restrict__ out, int t) {
  constexpr int O = GATE ? 128 : 64;
  constexpr int N2 = GATE ? 2 : 1;
  __shared__ __align__(16) char smem[132608];
  short* sm2 = (short*)smem;
  short* sS = (short*)smem;                  // overlay, stride 408
  float* sSx = (float*)(smem + 131072);      // [64][6]

  int tid = threadIdx.x;
  int L = tid & 63, w = tid >> 6;
  int i0 = blockIdx.x * 64;
  int b = blockIdx.y;
  int bcol = b * 64;

  // stage Sx slice (disjoint LDS region)
  for (int e = tid; e < 384; e += 256) {
    int il = e / 6, kc = e % 6;
    sSx[e] = Sx2[(size_t)((kc >> 1) * 512 + i0 + il) * 768 + t * 64 + b * 2 + (kc & 1)];
  }

  f32x4 acc[3][4];
#pragma unroll
  for (int m = 0; m < 3; ++m)
#pragma unroll
    for (int n = 0; n < 4; ++n) acc[m][n] = (f32x4)(0.f);

  // ---- pipelined main loop: 8 iters of BK=64, 3 Markidis combos per iter ----
  stage_tiles(sm2, 0, 0, GH, GL, Bhi, Blo, i0, bcol, L, w);
#pragma unroll 2
  for (int it = 0; it < 8; ++it) {
    int cur = it & 1;
    if (it < 7) {
      stage_tiles(sm2, cur ^ 1, (it + 1) << 6, GH, GL, Bhi, Blo, i0, bcol, L, w);
      asm volatile("s_waitcnt vmcnt(16)" ::: "memory");  // own stage(it) landed
    } else {
      asm volatile("s_waitcnt vmcnt(0)" ::: "memory");
    }
    __builtin_amdgcn_s_barrier();           // all waves' stage(it) landed
    __builtin_amdgcn_sched_barrier(0);
    mainloop_compute(sm2, cur, L, w, acc);
    asm volatile("" ::: "memory");
    __builtin_amdgcn_s_barrier();           // reads done before next overwrite
  }
  __builtin_amdgcn_sched_barrier(0);

  // ---- write S to LDS overlay as bf16 hi/lo ----
#pragma unroll
  for (int m = 0; m < 3; ++m)
#pragma unroll
    for (int n = 0; n < 4; ++n)
#pragma unroll
      for (int r = 0; r < 4; ++r) {
        int R = w * 48 + m * 16 + (L >> 4) * 4 + r;
        int il = R & 63, kk = R >> 6;
        int p = n * 16 + (L & 15);
        float v = acc[m][n][r];
        unsigned short hi = f2bf(v);
        sS[il * 408 + kk * 64 + p] = (short)hi;
        sS[il * 408 + 200 + kk * 64 + p] = (short)f2bf(v - bf2f(hi));
      }
  __syncthreads();

  // ---- epilogue MFMA: zr[64][O] over K = 3 sections x 192 ----
  int wn = w * (O / 4);
  f32x4 acc2[4][N2];
#pragma unroll
  for (int m = 0; m < 4; ++m)
#pragma unroll
    for (int n = 0; n < N2; ++n) acc2[m][n] = (f32x4)(0.f);

#pragma unroll
  for (int s = 0; s < 3; ++s) {
    const unsigned short* Wsrc = (s < 2) ? Whi : Wlo;
    int abase = (s == 1) ? 200 : 0;
#pragma unroll
    for (int f = 0; f < 6; ++f) {
      int k0 = f * 32 + (L >> 4) * 8;
      v8s af2[4], bf2[N2];
#pragma unroll
      for (int m = 0; m < 4; ++m)
        af2[m] = *(const v8s*)(sS + (m * 16 + (L & 15)) * 408 + abase + k0);
#pragma unroll
      for (int n = 0; n < N2; ++n)
        bf2[n] = *(const v8s*)(Wsrc + (size_t)(wn + n * 16 + (L & 15)) * 200 + k0);
#pragma unroll
      for (int m = 0; m < 4; ++m)
#pragma unroll
        for (int n = 0; n < N2; ++n)
          acc2[m][n] = __builtin_amdgcn_mfma_f32_16x16x32_bf16(af2[m], bf2[n], acc2[m][n], 0, 0, 0);
    }
  }

  // ---- x-part + bias + activation + state update ----
#pragma unroll
  for (int m = 0; m < 4; ++m) {
#pragma unroll
    for (int n = 0; n < N2; ++n) {
      int o = wn + n * 16 + (L & 15);
      int il0 = m * 16 + (L >> 4) * 4;
      float vals[4];
#pragma unroll
      for (int r = 0; r < 4; ++r) {
        float v = acc2[m][n][r] + bias[o];
#pragma unroll
        for (int kc = 0; kc < 6; ++kc) v += sSx[(il0 + r) * 6 + kc] * Wx[kc * O + o];
        vals[r] = v;
      }
      if (GATE) {
        float sg[4];
#pragma unroll
        for (int r = 0; r < 4; ++r) sg[r] = 1.f / (1.f + __expf(-vals[r]));
        if (o < 64) {
#pragma unroll
          for (int r = 0; r < 4; ++r)
            Z[((size_t)b * 512 + i0 + il0 + r) * 64 + o] = sg[r];
        } else {
          int col = bcol + (o - 64);
          size_t cb = (size_t)col * 512 + i0 + (((il0 >> 3) ^ (col & 7)) << 3) + (il0 & 7);
          u16x4 h4 = *(const u16x4*)(Hr_hi + cb);
          u16x4 l4 = *(const u16x4*)(Hr_lo + cb);
          u16x4 oh, ol;
#pragma unroll
          for (int r = 0; r < 4; ++r) {
            float h = bf2f(h4[r]) + bf2f(l4[r]);
            float rh = sg[r] * h;
            unsigned short hi = f2bf(rh);
            oh[r] = hi;
            ol[r] = f2bf(rh - bf2f(hi));
          }
          *(u16x4*)(Ohi + cb) = oh;
          *(u16x4*)(Olo + cb) = ol;
        }
      } else {
        int col = bcol + o;
        size_t cb = (size_t)col * 512 + i0 + (((il0 >> 3) ^ (col & 7)) << 3) + (il0 & 7);
        u16x4 h4 = *(const u16x4*)(Hr_hi + cb);
        u16x4 l4 = *(const u16x4*)(Hr_lo + cb);
        u16x4 oh, ol;
#pragma unroll
        for (int r = 0; r < 4; ++r) {
          float hc = tanhf(vals[r]);
          float z = Z[((size_t)b * 512 + i0 + il0 + r) * 64 + o];
          float h = bf2f(h4[r]) + bf2f(l4[r]);
          float hn = (1.f - z) * h + z * hc;
          unsigned short hi = f2bf(hn);
          oh[r] = hi;
          ol[r] = f2bf(hn - bf2f(hi));
          if (t == TT - 1) out[((size_t)b * 512 + i0 + il0 + r) * 64 + o] = hn;
        }
        *(u16x4*)(Ohi + cb) = oh;
        *(u16x4*)(Olo + cb) = ol;
      }
    }
  }
}

extern "C" void kernel_launch(void* const* d_in, const int* in_sizes, int n_in,
                              void* d_out, int out_size, void* d_ws, size_t ws_size,
                              hipStream_t stream) {
  const float* G      = (const float*)d_in[0];
  const float* x_seq  = (const float*)d_in[1];
  const float* init_h = (const float*)d_in[2];
  const float* Wg     = (const float*)d_in[3];
  const float* bg     = (const float*)d_in[4];
  const float* Wu     = (const float*)d_in[5];
  const float* bu     = (const float*)d_in[6];
  float* out = (float*)d_out;
  float* ws = (float*)d_ws;

  unsigned short* GHI  = (unsigned short*)(ws + OFF_GHI);
  unsigned short* GLO  = (unsigned short*)(ws + OFF_GLO);
  unsigned short* Xh   = (unsigned short*)(ws + OFF_XTH);
  unsigned short* Xl   = (unsigned short*)(ws + OFF_XTL);
  float* Sx2           = ws + OFF_SX;
  unsigned short* Hhi  = (unsigned short*)(ws + OFF_HHI);
  unsigned short* Hlo  = (unsigned short*)(ws + OFF_HLO);
  unsigned short* RHhi = (unsigned short*)(ws + OFF_RHHI);
  unsigned short* RHlo = (unsigned short*)(ws + OFF_RHLO);
  float* Z             = ws + OFF_Z;
  unsigned short* Whgh = (unsigned short*)(ws + OFF_WHGH);
  unsigned short* Whgl = (unsigned short*)(ws + OFF_WHGL);
  unsigned short* Whuh = (unsigned short*)(ws + OFF_WHUH);
  unsigned short* Whul = (unsigned short*)(ws + OFF_WHUL);
  float* Wxg           = ws + OFF_WXG;
  float* Wxu           = ws + OFF_WXU;

  // Prologue
  pack_g<<<3072, 256, 0, stream>>>(G, GHI, GLO);
  prep_xt2<<<1536, 256, 0, stream>>>(x_seq, Xh, Xl);
  prep_h2<<<4096, 256, 0, stream>>>(init_h, Hhi, Hlo);
  pack_w<<<149, 256, 0, stream>>>(Wg, Wu, Whgh, Whgl, Whuh, Whul, Wxg, Wxu);
  gemm_sx<<<dim3(12, 24), 256, 0, stream>>>(GHI, GLO, Xh, Xl, Sx2);

  for (int t = 0; t < TT; ++t) {
    fused_step<1><<<dim3(8, 32), 256, 0, stream>>>(GHI, GLO, Hhi, Hlo, Sx2, Whgh, Whgl,
                                                   Wxg, bg, Hhi, Hlo, RHhi, RHlo, Z, out, t);
    fused_step<0><<<dim3(8, 32), 256, 0, stream>>>(GHI, GLO, RHhi, RHlo, Sx2, Whuh, Whul,
                                                   Wxu, bu, Hhi, Hlo, Hhi, Hlo, Z, out, t);
  }
}